// Round 4
// baseline (166.313 us; speedup 1.0000x reference)
//
#include <hip/hip_runtime.h>
#include <hip/hip_cooperative_groups.h>
#include <math.h>

namespace cg = cooperative_groups;

#define D 256
#define N 16
#define R 16

// workspace float offsets (192 KB used)
#define WS_X1C  0
#define WS_RES1 16384
#define WS_X2C  32768

__device__ __forceinline__ float silu_f(float x) { return x / (1.0f + expf(-x)); }
__device__ __forceinline__ float softplus_f(float x) {
    return fmaxf(x, 0.0f) + log1pf(expf(-fabsf(x)));
}

// One cooperative kernel. Grid = 4*batch blocks x 256 threads.
// Phase 1: block g handles batch b=g>>2, dot-range quarter qb=g&3 of the 768
//   in_w dots (x1c | res1 | x2c) -> ws.   grid.sync()
// Phases 2-4: block b (< batch) does conv/silu, xproj, dt/scan/y, out_w,
//   final rmsnorm entirely in LDS -> out. Blocks >= batch exit.
__global__ __launch_bounds__(256) void k_mamba_all(
    const float* __restrict__ x1_in, const float* __restrict__ x2_in,
    const float* __restrict__ norm_w, const float* __restrict__ conv_w,
    const float* __restrict__ conv_b, const float* __restrict__ in_w,
    const float* __restrict__ xproj_w, const float* __restrict__ dt_w,
    const float* __restrict__ dt_b, const float* __restrict__ out_w,
    const float* __restrict__ A_log, const float* __restrict__ Dp,
    const int* __restrict__ l_ptr, float* __restrict__ ws,
    float* __restrict__ out)
{
    __shared__ float s_n1[D];
    __shared__ float s_n2[D];
    __shared__ float s_x2s[4][D];
    __shared__ float s_xdbl[4][48];   // [tc][delta(16)|B(16)|C(16)]
    __shared__ float s_y[D];
    __shared__ float s_z[D];
    __shared__ float s_red[8];

    const int t = threadIdx.x;
    const int g = blockIdx.x;
    const int l = *l_ptr;

    // ================= phase 1: rmsnorm + in_w matvec =================
    {
        const int b  = g >> 2;
        const int qb = g & 3;
        const float v1 = x1_in[b * D + t];
        const float v2 = x2_in[b * D + t];
        float p1 = v1 * v1, p2 = v2 * v2;
        #pragma unroll
        for (int off = 32; off >= 1; off >>= 1) {
            p1 += __shfl_down(p1, off, 64);
            p2 += __shfl_down(p2, off, 64);
        }
        if ((t & 63) == 0) { s_red[t >> 6] = p1; s_red[4 + (t >> 6)] = p2; }
        __syncthreads();
        const float ss1 = s_red[0] + s_red[1] + s_red[2] + s_red[3];
        const float ss2 = s_red[4] + s_red[5] + s_red[6] + s_red[7];
        const float wn = norm_w[t];
        s_n1[t] = v1 * rsqrtf(ss1 * (1.0f / D) + 1e-5f) * wn;
        s_n2[t] = v2 * rsqrtf(ss2 * (1.0f / D) + 1e-5f) * wn;
        __syncthreads();

        const int q = t & 3;
        for (int it = 0; it < 3; ++it) {
            const int o   = qb * 192 + it * 64 + (t >> 2);
            const int row = (o >= 512) ? (o - 512) : o;
            const float* __restrict__ wr = in_w + (size_t)row * D;
            const float* __restrict__ xs = (o >= 512) ? s_n2 : s_n1;
            float acc = 0.0f;
            #pragma unroll
            for (int k = 0; k < 16; ++k) {
                const int e = q * 4 + 16 * k;
                const float4 w4 = *(const float4*)(wr + e);
                const float4 n4 = *(const float4*)(xs + e);
                acc += w4.x*n4.x + w4.y*n4.y + w4.z*n4.z + w4.w*n4.w;
            }
            acc += __shfl_xor(acc, 1, 64);
            acc += __shfl_xor(acc, 2, 64);
            if (q == 0) {
                const int jj = o & 255;
                float* dst = (o < 256) ? (ws + WS_X1C)
                           : (o < 512) ? (ws + WS_RES1)
                                       : (ws + WS_X2C);
                dst[b * D + jj] = acc;
            }
        }
    }

    __threadfence();
    cg::this_grid().sync();

    const int nbatch = gridDim.x >> 2;
    if (g >= nbatch) return;
    const int b = g;

    // ================= phase 2: conv + silu =================
    float x1s[4];
    float res1;
    {
        const float x1c = ws[WS_X1C + b * D + t];
        const float x2c = ws[WS_X2C + b * D + t];
        res1 = ws[WS_RES1 + b * D + t];
        const float4 cw = *(const float4*)(conv_w + 4 * t);
        const float cb  = conv_b[t];
        float ksum[4];
        ksum[0] = cw.w;
        ksum[1] = cw.z + cw.w;
        ksum[2] = cw.y + cw.z + cw.w;
        ksum[3] = cw.x + cw.y + cw.z + cw.w;
        #pragma unroll
        for (int tc = 0; tc < 4; ++tc) {
            x1s[tc] = silu_f(ksum[tc] * x1c + cb);
            s_x2s[tc][t] = silu_f(ksum[tc] * x2c + cb);
        }
    }
    __syncthreads();

    // ================= phase 3: xproj (192 dots x 4 thr, 3 iters) =========
    {
        const int q = t & 3;
        for (int it = 0; it < 3; ++it) {
            const int dotid = it * 64 + (t >> 2);
            const int tc = dotid / 48;
            const int o  = dotid % 48;
            const float* __restrict__ pr = xproj_w + (size_t)o * D;
            const float* __restrict__ xs = s_x2s[tc];
            float acc = 0.0f;
            #pragma unroll
            for (int k = 0; k < 16; ++k) {
                const int e = q * 4 + 16 * k;
                const float4 p4 = *(const float4*)(pr + e);
                const float4 x4 = *(const float4*)(xs + e);
                acc += p4.x*x4.x + p4.y*x4.y + p4.z*x4.z + p4.w*x4.w;
            }
            acc += __shfl_xor(acc, 1, 64);
            acc += __shfl_xor(acc, 2, 64);
            if (q == 0) s_xdbl[tc][o] = acc;
        }
    }
    __syncthreads();

    // ================= phase 4: delta, scan, y =================
    {
        const int j = t;
        const float* __restrict__ dtrow = dt_w + (size_t)j * R;
        float dtr[R];
        #pragma unroll
        for (int qq = 0; qq < R; ++qq) dtr[qq] = dtrow[qq];
        const float dtb = dt_b[j];
        float delta[4];
        #pragma unroll
        for (int tc = 0; tc < 4; ++tc) {
            float acc = 0.0f;
            #pragma unroll
            for (int qq = 0; qq < R; ++qq) acc += s_xdbl[tc][qq] * dtr[qq];
            delta[tc] = softplus_f(acc + dtb);
        }
        const float* __restrict__ arow = A_log + (size_t)j * N;
        float Aa[N];
        #pragma unroll
        for (int n = 0; n < N; ++n) Aa[n] = -expf(arow[n]);
        float h[N];
        #pragma unroll
        for (int n = 0; n < N; ++n) h[n] = 0.0f;
        const int nexp = (l < 3) ? l : 3;
        for (int tt = 0; tt < nexp; ++tt) {
            const float dl = delta[tt];
            const float du = dl * x1s[tt];
            #pragma unroll
            for (int n = 0; n < N; ++n) {
                const float dA = expf(dl * Aa[n]);
                h[n] = dA * h[n] + du * s_xdbl[tt][16 + n];
            }
        }
        if (l > 3) {
            const float dl = delta[3];
            const float du = dl * x1s[3];
            const float steps = (float)(l - 3);
            #pragma unroll
            for (int n = 0; n < N; ++n) {
                const float z   = dl * Aa[n];      // z < 0
                const float em1 = expm1f(z);
                const float emN = expm1f(steps * z);
                const float ratio = (em1 != 0.0f) ? (emN / em1) : steps;
                const float pw = emN + 1.0f;       // dA^steps
                h[n] = pw * h[n] + du * s_xdbl[3][16 + n] * ratio;
            }
        }
        const int fc = ((l - 1) < 3) ? (l - 1) : 3;
        float y = 0.0f;
        #pragma unroll
        for (int n = 0; n < N; ++n) y += h[n] * s_xdbl[fc][32 + n];
        y += x1s[fc] * Dp[j];
        y *= silu_f(res1);
        s_y[j] = y;
    }
    __syncthreads();

    // ================= phase 5: out_w matvec (256 dots x 4 thr, 4 iters) ==
    {
        const int q = t & 3;
        for (int it = 0; it < 4; ++it) {
            const int dotid = it * 64 + (t >> 2);
            const float* __restrict__ orow = out_w + (size_t)dotid * D;
            float acc = 0.0f;
            #pragma unroll
            for (int k = 0; k < 16; ++k) {
                const int e = q * 4 + 16 * k;
                const float4 w4 = *(const float4*)(orow + e);
                const float4 y4 = *(const float4*)(s_y + e);
                acc += w4.x*y4.x + w4.y*y4.y + w4.z*y4.z + w4.w*y4.w;
            }
            acc += __shfl_xor(acc, 1, 64);
            acc += __shfl_xor(acc, 2, 64);
            if (q == 0) s_z[dotid] = acc;
        }
    }
    __syncthreads();

    // ================= phase 6: final rmsnorm =================
    {
        const float zz = s_z[t];
        float p = zz * zz;
        #pragma unroll
        for (int off = 32; off >= 1; off >>= 1) p += __shfl_down(p, off, 64);
        if ((t & 63) == 0) s_red[t >> 6] = p;
        __syncthreads();
        const float ss = s_red[0] + s_red[1] + s_red[2] + s_red[3];
        out[b * D + t] = zz * rsqrtf(ss * (1.0f / D) + 1e-5f) * norm_w[t];
    }
}

extern "C" void kernel_launch(void* const* d_in, const int* in_sizes, int n_in,
                              void* d_out, int out_size, void* d_ws, size_t ws_size,
                              hipStream_t stream) {
    const float* x1      = (const float*)d_in[0];
    const float* x2      = (const float*)d_in[1];
    const float* norm_w  = (const float*)d_in[2];
    const float* conv_w  = (const float*)d_in[3];
    const float* conv_b  = (const float*)d_in[4];
    const float* in_w    = (const float*)d_in[5];
    const float* xproj_w = (const float*)d_in[6];
    const float* dt_w    = (const float*)d_in[7];
    const float* dt_b    = (const float*)d_in[8];
    const float* out_w   = (const float*)d_in[9];
    const float* A_log   = (const float*)d_in[10];
    const float* Dp      = (const float*)d_in[11];
    const int*   l_ptr   = (const int*)d_in[12];
    float* out = (float*)d_out;
    float* ws  = (float*)d_ws;

    const int batch = in_sizes[0] / D;   // 64

    void* args[] = {
        (void*)&x1, (void*)&x2, (void*)&norm_w, (void*)&conv_w, (void*)&conv_b,
        (void*)&in_w, (void*)&xproj_w, (void*)&dt_w, (void*)&dt_b, (void*)&out_w,
        (void*)&A_log, (void*)&Dp, (void*)&l_ptr, (void*)&ws, (void*)&out
    };
    hipLaunchCooperativeKernel((const void*)k_mamba_all,
                               dim3(batch * 4), dim3(256), args, 0, stream);
}

// Round 5
// 99.036 us; speedup vs baseline: 1.6793x; 1.6793x over previous
//
#include <hip/hip_runtime.h>
#include <math.h>

#define D 256
#define N 16
#define R 16

__device__ __forceinline__ float silu_f(float x) { return x / (1.0f + expf(-x)); }
__device__ __forceinline__ float softplus_f(float x) {
    return fmaxf(x, 0.0f) + log1pf(expf(-fabsf(x)));
}

// ONE kernel, one block per batch, 1024 threads (16 waves). All intermediates
// in LDS; no workspace, no cross-block communication.
// Phases: rmsnorm -> in_w (x1c&x2c share weight rows) -> conv/silu -> xproj
//         -> dt/scan (closed-form tail) -> out_w -> final rmsnorm.
__global__ __launch_bounds__(1024) void k_mamba_fused(
    const float* __restrict__ x1_in, const float* __restrict__ x2_in,
    const float* __restrict__ norm_w, const float* __restrict__ conv_w,
    const float* __restrict__ conv_b, const float* __restrict__ in_w,
    const float* __restrict__ xproj_w, const float* __restrict__ dt_w,
    const float* __restrict__ dt_b, const float* __restrict__ out_w,
    const float* __restrict__ A_log, const float* __restrict__ Dp,
    const int* __restrict__ l_ptr, float* __restrict__ out)
{
    __shared__ float s_n1[D];
    __shared__ float s_n2[D];
    __shared__ float s_x1c[D];
    __shared__ float s_x2c[D];
    __shared__ float s_res1[D];
    __shared__ float s_x2s[4][D];
    __shared__ float s_xdbl[4][48];   // [tc][delta(16)|B(16)|C(16)]
    __shared__ float s_y[D];
    __shared__ float s_z[D];
    __shared__ float s_red[8];

    const int t = threadIdx.x;
    const int b = blockIdx.x;
    const int l = *l_ptr;
    const int q   = t & 3;      // quarter within a dot
    const int dot = t >> 2;     // 0..255

    // ---- phase 1: rmsnorm(x1), rmsnorm(x2) (threads 0..255) ----
    float v1 = 0.0f, v2 = 0.0f;
    if (t < D) {
        v1 = x1_in[b * D + t];
        v2 = x2_in[b * D + t];
        float p1 = v1 * v1, p2 = v2 * v2;
        #pragma unroll
        for (int off = 32; off >= 1; off >>= 1) {
            p1 += __shfl_down(p1, off, 64);
            p2 += __shfl_down(p2, off, 64);
        }
        if ((t & 63) == 0) { s_red[t >> 6] = p1; s_red[4 + (t >> 6)] = p2; }
    }
    __syncthreads();
    if (t < D) {
        const float ss1 = s_red[0] + s_red[1] + s_red[2] + s_red[3];
        const float ss2 = s_red[4] + s_red[5] + s_red[6] + s_red[7];
        const float wn = norm_w[t];
        s_n1[t] = v1 * rsqrtf(ss1 * (1.0f / D) + 1e-5f) * wn;
        s_n2[t] = v2 * rsqrtf(ss2 * (1.0f / D) + 1e-5f) * wn;
    }
    __syncthreads();

    // ---- phase 2: in_w matvec, 4 threads/dot ----
    // it0: row = dot (0..255): x1c = w.n1, x2c = w.n2 (shared weight load)
    {
        const float* __restrict__ wr = in_w + (size_t)dot * D;
        float a1 = 0.0f, a2 = 0.0f;
        #pragma unroll
        for (int k = 0; k < 16; ++k) {
            const int e = q * 4 + 16 * k;
            const float4 w4 = *(const float4*)(wr + e);
            const float4 n14 = *(const float4*)(s_n1 + e);
            const float4 n24 = *(const float4*)(s_n2 + e);
            a1 += w4.x*n14.x + w4.y*n14.y + w4.z*n14.z + w4.w*n14.w;
            a2 += w4.x*n24.x + w4.y*n24.y + w4.z*n24.z + w4.w*n24.w;
        }
        a1 += __shfl_xor(a1, 1, 64); a1 += __shfl_xor(a1, 2, 64);
        a2 += __shfl_xor(a2, 1, 64); a2 += __shfl_xor(a2, 2, 64);
        if (q == 0) { s_x1c[dot] = a1; s_x2c[dot] = a2; }
    }
    // it1: row = 256+dot: res1 = w.n1
    {
        const float* __restrict__ wr = in_w + (size_t)(D + dot) * D;
        float a3 = 0.0f;
        #pragma unroll
        for (int k = 0; k < 16; ++k) {
            const int e = q * 4 + 16 * k;
            const float4 w4 = *(const float4*)(wr + e);
            const float4 n14 = *(const float4*)(s_n1 + e);
            a3 += w4.x*n14.x + w4.y*n14.y + w4.z*n14.z + w4.w*n14.w;
        }
        a3 += __shfl_xor(a3, 1, 64); a3 += __shfl_xor(a3, 2, 64);
        if (q == 0) s_res1[dot] = a3;
    }
    __syncthreads();

    // ---- phase 3: conv + silu (threads 0..255) ----
    float x1s[4];
    if (t < D) {
        const float x1c = s_x1c[t];
        const float x2c = s_x2c[t];
        const float4 cw = *(const float4*)(conv_w + 4 * t);
        const float cb  = conv_b[t];
        float ksum[4];
        ksum[0] = cw.w;
        ksum[1] = cw.z + cw.w;
        ksum[2] = cw.y + cw.z + cw.w;
        ksum[3] = cw.x + cw.y + cw.z + cw.w;
        #pragma unroll
        for (int tc = 0; tc < 4; ++tc) {
            x1s[tc] = silu_f(ksum[tc] * x1c + cb);
            s_x2s[tc][t] = silu_f(ksum[tc] * x2c + cb);
        }
    }
    __syncthreads();

    // ---- phase 4: xproj, 192 dots x 4 threads (threads 0..767) ----
    if (t < 768) {
        const int tc = dot / 48;
        const int o  = dot % 48;
        const float* __restrict__ pr = xproj_w + (size_t)o * D;
        const float* __restrict__ xs = s_x2s[tc];
        float acc = 0.0f;
        #pragma unroll
        for (int k = 0; k < 16; ++k) {
            const int e = q * 4 + 16 * k;
            const float4 p4 = *(const float4*)(pr + e);
            const float4 x4 = *(const float4*)(xs + e);
            acc += p4.x*x4.x + p4.y*x4.y + p4.z*x4.z + p4.w*x4.w;
        }
        acc += __shfl_xor(acc, 1, 64);
        acc += __shfl_xor(acc, 2, 64);
        if (q == 0) s_xdbl[tc][o] = acc;
    }
    __syncthreads();

    // ---- phase 5: delta, scan, y (threads 0..255) ----
    if (t < D) {
        const int j = t;
        const float* __restrict__ dtrow = dt_w + (size_t)j * R;
        float dtr[R];
        #pragma unroll
        for (int qq = 0; qq < R; ++qq) dtr[qq] = dtrow[qq];
        const float dtb = dt_b[j];
        float delta[4];
        #pragma unroll
        for (int tc = 0; tc < 4; ++tc) {
            float acc = 0.0f;
            #pragma unroll
            for (int qq = 0; qq < R; ++qq) acc += s_xdbl[tc][qq] * dtr[qq];
            delta[tc] = softplus_f(acc + dtb);
        }
        const float* __restrict__ arow = A_log + (size_t)j * N;
        float Aa[N];
        #pragma unroll
        for (int n = 0; n < N; ++n) Aa[n] = -expf(arow[n]);
        float h[N];
        #pragma unroll
        for (int n = 0; n < N; ++n) h[n] = 0.0f;
        const int nexp = (l < 3) ? l : 3;
        for (int tt = 0; tt < nexp; ++tt) {
            const float dl = delta[tt];
            const float du = dl * x1s[tt];
            #pragma unroll
            for (int n = 0; n < N; ++n) {
                const float dA = expf(dl * Aa[n]);
                h[n] = dA * h[n] + du * s_xdbl[tt][16 + n];
            }
        }
        if (l > 3) {
            const float dl = delta[3];
            const float du = dl * x1s[3];
            const float steps = (float)(l - 3);
            #pragma unroll
            for (int n = 0; n < N; ++n) {
                const float z   = dl * Aa[n];      // z < 0
                const float em1 = expm1f(z);
                const float emN = expm1f(steps * z);
                const float ratio = (em1 != 0.0f) ? (emN / em1) : steps;
                const float pw = emN + 1.0f;       // dA^steps
                h[n] = pw * h[n] + du * s_xdbl[3][16 + n] * ratio;
            }
        }
        const int fc = ((l - 1) < 3) ? (l - 1) : 3;
        float y = 0.0f;
        #pragma unroll
        for (int n = 0; n < N; ++n) y += h[n] * s_xdbl[fc][32 + n];
        y += x1s[fc] * Dp[j];
        y *= silu_f(s_res1[j]);
        s_y[j] = y;
    }
    __syncthreads();

    // ---- phase 6: out_w matvec, 256 dots x 4 threads (all 1024) ----
    {
        const float* __restrict__ orow = out_w + (size_t)dot * D;
        float acc = 0.0f;
        #pragma unroll
        for (int k = 0; k < 16; ++k) {
            const int e = q * 4 + 16 * k;
            const float4 w4 = *(const float4*)(orow + e);
            const float4 y4 = *(const float4*)(s_y + e);
            acc += w4.x*y4.x + w4.y*y4.y + w4.z*y4.z + w4.w*y4.w;
        }
        acc += __shfl_xor(acc, 1, 64);
        acc += __shfl_xor(acc, 2, 64);
        if (q == 0) s_z[dot] = acc;
    }
    __syncthreads();

    // ---- phase 7: final rmsnorm (threads 0..255) ----
    if (t < D) {
        const float zz = s_z[t];
        float p = zz * zz;
        #pragma unroll
        for (int off = 32; off >= 1; off >>= 1) p += __shfl_down(p, off, 64);
        if ((t & 63) == 0) s_red[t >> 6] = p;
    }
    __syncthreads();
    if (t < D) {
        const float ss = s_red[0] + s_red[1] + s_red[2] + s_red[3];
        out[b * D + t] = s_z[t] * rsqrtf(ss * (1.0f / D) + 1e-5f) * norm_w[t];
    }
}

extern "C" void kernel_launch(void* const* d_in, const int* in_sizes, int n_in,
                              void* d_out, int out_size, void* d_ws, size_t ws_size,
                              hipStream_t stream) {
    const float* x1      = (const float*)d_in[0];
    const float* x2      = (const float*)d_in[1];
    const float* norm_w  = (const float*)d_in[2];
    const float* conv_w  = (const float*)d_in[3];
    const float* conv_b  = (const float*)d_in[4];
    const float* in_w    = (const float*)d_in[5];
    const float* xproj_w = (const float*)d_in[6];
    const float* dt_w    = (const float*)d_in[7];
    const float* dt_b    = (const float*)d_in[8];
    const float* out_w   = (const float*)d_in[9];
    const float* A_log   = (const float*)d_in[10];
    const float* Dp      = (const float*)d_in[11];
    const int*   l_ptr   = (const int*)d_in[12];
    float* out = (float*)d_out;

    const int batch = in_sizes[0] / D;   // 64
    k_mamba_fused<<<dim3(batch), dim3(1024), 0, stream>>>(
        x1, x2, norm_w, conv_w, conv_b, in_w, xproj_w, dt_w, dt_b,
        out_w, A_log, Dp, l_ptr, out);
}

// Round 6
// 94.241 us; speedup vs baseline: 1.7648x; 1.0509x over previous
//
#include <hip/hip_runtime.h>
#include <math.h>

#define D 256
#define N 16
#define R 16

// workspace float offsets (192 KB used)
#define WS_X1C  0
#define WS_RES1 16384
#define WS_X2C  32768

__device__ __forceinline__ float silu_f(float x) { return x / (1.0f + expf(-x)); }
__device__ __forceinline__ float softplus_f(float x) {
    return fmaxf(x, 0.0f) + log1pf(expf(-fabsf(x)));
}

// ---------------- K1: rmsnorm + in_w matvec ----------------
// grid: 768 blocks (12/batch), 256 threads, 64 dots/block.
// Weight loads are issued at entry (before the norm) so the 256 KB weight
// stream overlaps the norm's load+reduce chain.
__global__ __launch_bounds__(256) void k_inw(
    const float* __restrict__ x1_in, const float* __restrict__ x2_in,
    const float* __restrict__ norm_w, const float* __restrict__ in_w,
    float* __restrict__ ws)
{
    __shared__ float s_n[D];
    __shared__ float s_red[4];
    const int t  = threadIdx.x;
    const int g0 = blockIdx.x * 64;
    const int b  = g0 / 768;
    const int o0 = g0 % 768;          // multiple of 64; region-uniform per block
    const bool use2 = (o0 >= 512);
    const int q = t & 3;
    const int o = o0 + (t >> 2);
    const int row = (o >= 512) ? (o - 512) : o;

    // ---- prefetch weights (issues immediately, consumed after norm) ----
    const float* __restrict__ wr = in_w + (size_t)row * D;
    float4 w[16];
    #pragma unroll
    for (int k = 0; k < 16; ++k) w[k] = *(const float4*)(wr + q * 4 + 16 * k);

    // ---- rmsnorm of the one input row this block needs ----
    const float* __restrict__ xrow = (use2 ? x2_in : x1_in) + (size_t)b * D;
    const float v = xrow[t];
    float p = v * v;
    #pragma unroll
    for (int off = 32; off >= 1; off >>= 1) p += __shfl_down(p, off, 64);
    if ((t & 63) == 0) s_red[t >> 6] = p;
    __syncthreads();
    const float ss = s_red[0] + s_red[1] + s_red[2] + s_red[3];
    s_n[t] = v * rsqrtf(ss * (1.0f / D) + 1e-5f) * norm_w[t];
    __syncthreads();

    // ---- dot: 4 threads/dot, interleaved quarters ----
    float acc = 0.0f;
    #pragma unroll
    for (int k = 0; k < 16; ++k) {
        const int e = q * 4 + 16 * k;
        const float4 n4 = *(const float4*)(s_n + e);
        acc += w[k].x*n4.x + w[k].y*n4.y + w[k].z*n4.z + w[k].w*n4.w;
    }
    acc += __shfl_xor(acc, 1, 64);
    acc += __shfl_xor(acc, 2, 64);
    if (q == 0) {
        const int jj = o & 255;
        float* dst = (o < 256) ? (ws + WS_X1C)
                   : (o < 512) ? (ws + WS_RES1)
                               : (ws + WS_X2C);
        dst[b * D + jj] = acc;
    }
}

// ---------------- K2: conv+silu, xproj, dt/scan/y, out_w, rmsnorm ---------
// grid: 64 blocks (one per batch), 1024 threads. Entry-prefetch of all
// tid-addressable operands (ws scalars, conv row, dt row, A_log row, half of
// the out_w row-quarter) overlaps cold loads with the dependent chain.
__global__ __launch_bounds__(1024) void k_fused(
    const float* __restrict__ conv_w, const float* __restrict__ conv_b,
    const float* __restrict__ xproj_w, const float* __restrict__ dt_w,
    const float* __restrict__ dt_b, const float* __restrict__ A_log,
    const float* __restrict__ Dp, const int* __restrict__ l_ptr,
    const float* __restrict__ out_w, const float* __restrict__ norm_w,
    const float* __restrict__ ws, float* __restrict__ out)
{
    __shared__ float s_x2s[4][D];
    __shared__ float s_xdbl[4][48];   // [tc][delta(16)|B(16)|C(16)]
    __shared__ float s_y[D];
    __shared__ float s_z[D];
    __shared__ float s_red[4];
    const int b = blockIdx.x;
    const int t = threadIdx.x;
    const int l = *l_ptr;
    const int q   = t & 3;
    const int dot = t >> 2;

    // ---- entry prefetch ----
    const float* __restrict__ orow = out_w + (size_t)dot * D;
    float4 wo[8];
    #pragma unroll
    for (int k = 0; k < 8; ++k) wo[k] = *(const float4*)(orow + q * 4 + 16 * k);

    float x1c = 0.0f, x2c = 0.0f, res1 = 0.0f, cb = 0.0f, dtb = 0.0f,
          dpj = 0.0f, wnj = 0.0f;
    float4 cw = make_float4(0.f, 0.f, 0.f, 0.f);
    float dtr[R];
    float alog[N];
    if (t < D) {
        x1c  = ws[WS_X1C  + b * D + t];
        x2c  = ws[WS_X2C  + b * D + t];
        res1 = ws[WS_RES1 + b * D + t];
        cw   = *(const float4*)(conv_w + 4 * t);
        cb   = conv_b[t];
        dtb  = dt_b[t];
        dpj  = Dp[t];
        wnj  = norm_w[t];
        const float* __restrict__ dtrow = dt_w + (size_t)t * R;
        #pragma unroll
        for (int qq = 0; qq < R; ++qq) dtr[qq] = dtrow[qq];
        const float* __restrict__ arow = A_log + (size_t)t * N;
        #pragma unroll
        for (int n = 0; n < N; ++n) alog[n] = arow[n];
    }

    // ---- phase A: conv + silu (threads 0..255) ----
    float x1s[4];
    if (t < D) {
        float ksum[4];
        ksum[0] = cw.w;
        ksum[1] = cw.z + cw.w;
        ksum[2] = cw.y + cw.z + cw.w;
        ksum[3] = cw.x + cw.y + cw.z + cw.w;
        #pragma unroll
        for (int tc = 0; tc < 4; ++tc) {
            x1s[tc] = silu_f(ksum[tc] * x1c + cb);
            s_x2s[tc][t] = silu_f(ksum[tc] * x2c + cb);
        }
    }
    __syncthreads();

    // ---- phase B: xproj, 192 dots x 4 threads (threads 0..767) ----
    if (t < 768) {
        const int tc = dot / 48;
        const int o  = dot % 48;
        const float* __restrict__ pr = xproj_w + (size_t)o * D;
        const float* __restrict__ xs = s_x2s[tc];
        float acc = 0.0f;
        #pragma unroll
        for (int k = 0; k < 16; ++k) {
            const int e = q * 4 + 16 * k;
            const float4 p4 = *(const float4*)(pr + e);
            const float4 x4 = *(const float4*)(xs + e);
            acc += p4.x*x4.x + p4.y*x4.y + p4.z*x4.z + p4.w*x4.w;
        }
        acc += __shfl_xor(acc, 1, 64);
        acc += __shfl_xor(acc, 2, 64);
        if (q == 0) s_xdbl[tc][o] = acc;
    }
    __syncthreads();

    // ---- phase C: delta, scan (closed-form tail), y (threads 0..255) ----
    if (t < D) {
        float delta[4];
        #pragma unroll
        for (int tc = 0; tc < 4; ++tc) {
            float acc = 0.0f;
            #pragma unroll
            for (int qq = 0; qq < R; ++qq) acc += s_xdbl[tc][qq] * dtr[qq];
            delta[tc] = softplus_f(acc + dtb);
        }
        float Aa[N];
        #pragma unroll
        for (int n = 0; n < N; ++n) Aa[n] = -expf(alog[n]);
        float h[N];
        #pragma unroll
        for (int n = 0; n < N; ++n) h[n] = 0.0f;
        const int nexp = (l < 3) ? l : 3;
        for (int tt = 0; tt < nexp; ++tt) {
            const float dl = delta[tt];
            const float du = dl * x1s[tt];
            #pragma unroll
            for (int n = 0; n < N; ++n) {
                const float dA = expf(dl * Aa[n]);
                h[n] = dA * h[n] + du * s_xdbl[tt][16 + n];
            }
        }
        if (l > 3) {
            const float dl = delta[3];
            const float du = dl * x1s[3];
            const float steps = (float)(l - 3);
            #pragma unroll
            for (int n = 0; n < N; ++n) {
                const float z   = dl * Aa[n];      // z < 0
                const float em1 = expm1f(z);
                const float emN = expm1f(steps * z);
                const float ratio = (em1 != 0.0f) ? (emN / em1) : steps;
                const float pw = emN + 1.0f;       // dA^steps
                h[n] = pw * h[n] + du * s_xdbl[3][16 + n] * ratio;
            }
        }
        const int fc = ((l - 1) < 3) ? (l - 1) : 3;
        float y = 0.0f;
        #pragma unroll
        for (int n = 0; n < N; ++n) y += h[n] * s_xdbl[fc][32 + n];
        y += x1s[fc] * dpj;
        y *= silu_f(res1);
        s_y[t] = y;
    }
    __syncthreads();

    // ---- phase D: out_w matvec, 256 dots x 4 threads (all 1024) ----
    {
        // issue the remaining half of the weight row first
        float4 wo2[8];
        #pragma unroll
        for (int k = 0; k < 8; ++k)
            wo2[k] = *(const float4*)(orow + q * 4 + 16 * (8 + k));
        float acc = 0.0f;
        #pragma unroll
        for (int k = 0; k < 8; ++k) {
            const int e = q * 4 + 16 * k;
            const float4 y4 = *(const float4*)(s_y + e);
            acc += wo[k].x*y4.x + wo[k].y*y4.y + wo[k].z*y4.z + wo[k].w*y4.w;
        }
        #pragma unroll
        for (int k = 0; k < 8; ++k) {
            const int e = q * 4 + 16 * (8 + k);
            const float4 y4 = *(const float4*)(s_y + e);
            acc += wo2[k].x*y4.x + wo2[k].y*y4.y + wo2[k].z*y4.z + wo2[k].w*y4.w;
        }
        acc += __shfl_xor(acc, 1, 64);
        acc += __shfl_xor(acc, 2, 64);
        if (q == 0) s_z[dot] = acc;
    }
    __syncthreads();

    // ---- phase E: final rmsnorm (threads 0..255) ----
    if (t < D) {
        const float zz = s_z[t];
        float p = zz * zz;
        #pragma unroll
        for (int off = 32; off >= 1; off >>= 1) p += __shfl_down(p, off, 64);
        if ((t & 63) == 0) s_red[t >> 6] = p;
    }
    __syncthreads();
    if (t < D) {
        const float ss = s_red[0] + s_red[1] + s_red[2] + s_red[3];
        out[b * D + t] = s_z[t] * rsqrtf(ss * (1.0f / D) + 1e-5f) * wnj;
    }
}

extern "C" void kernel_launch(void* const* d_in, const int* in_sizes, int n_in,
                              void* d_out, int out_size, void* d_ws, size_t ws_size,
                              hipStream_t stream) {
    const float* x1      = (const float*)d_in[0];
    const float* x2      = (const float*)d_in[1];
    const float* norm_w  = (const float*)d_in[2];
    const float* conv_w  = (const float*)d_in[3];
    const float* conv_b  = (const float*)d_in[4];
    const float* in_w    = (const float*)d_in[5];
    const float* xproj_w = (const float*)d_in[6];
    const float* dt_w    = (const float*)d_in[7];
    const float* dt_b    = (const float*)d_in[8];
    const float* out_w   = (const float*)d_in[9];
    const float* A_log   = (const float*)d_in[10];
    const float* Dp      = (const float*)d_in[11];
    const int*   l_ptr   = (const int*)d_in[12];
    float* out = (float*)d_out;
    float* ws  = (float*)d_ws;

    const int batch = in_sizes[0] / D;   // 64

    k_inw<<<dim3(batch * 12), dim3(256), 0, stream>>>(x1, x2, norm_w, in_w, ws);
    k_fused<<<dim3(batch), dim3(1024), 0, stream>>>(conv_w, conv_b, xproj_w,
                                                    dt_w, dt_b, A_log, Dp, l_ptr,
                                                    out_w, norm_w, ws, out);
}